// Round 17
// baseline (121.757 us; speedup 1.0000x reference)
//
#include <hip/hip_runtime.h>
#include <math.h>

// fp16-MFMA flash attention (no-max softmax), S=8192, D=128, fp32 in/out.
// R17 = R12 champion + ONE change: V frags read DIRECT from global (L2/L1
// broadcast) into registers, issued ~600+ cyc before consumption (after the
// barrier / after softmax(0)) so latency is covered -- unlike R10 where both
// K and V were direct and consumed immediately. K stays in LDS (staged via
// async global_load_lds, 64-key dbuf). Halves DS-pipe read traffic and
// removes the PV-section lgkm wait.
// Core: transposed-S fp16 QK^T (A=K,B=Q), dual-S accumulators, in-register
// P transpose via shfl_xor(32), per-slice partial stores + reduce/norm.
// Graveyard: R8/R11 fusion, R9/R14 occupancy, R10 all-direct, R13 source
// pipelining, R15 64q/wave, R16 wave de-phasing.

typedef _Float16 f16x8 __attribute__((ext_vector_type(8)));
typedef float    f32x16 __attribute__((ext_vector_type(16)));

constexpr int S_LEN = 8192;
constexpr int D_K   = 128;
constexpr int NSLICE = 8;
constexpr int ITERS2 = (S_LEN / NSLICE) / 64;   // 16 iters of 64 keys

// ws: Lpart[8][8192] fp32 (256 KB) | K frags 2 MB | V frags 2 MB | Opart[7]x4MB
constexpr size_t WS_L_OFF = 0;
constexpr size_t KF_OFF   = 262144;
constexpr size_t VF_OFF   = KF_OFF + (size_t)256 * 8192;
constexpr size_t PART_OFF = VF_OFF + (size_t)256 * 8192;
constexpr size_t WS_NEED  = PART_OFF + (size_t)7 * S_LEN * D_K * 4;  // ~32.5 MB

#define CSCALE (0.08838834764831845f * 1.44269504088896340736f)

union UH8 { _Float16 h[8]; uint4 q; f16x8 v; };
union UF4 { unsigned u[4]; uint4 q; f16x8 v; };

__device__ inline void async16(const uint4* g, uint4* l) {
  __builtin_amdgcn_global_load_lds(
      (const __attribute__((address_space(1))) unsigned int*)g,
      (__attribute__((address_space(3))) unsigned int*)l, 16, 0, 0);
}

// ---------------- prep: frag build (+ zero out/ws_l if atomic path) ----------
template <bool ZOUT>
__global__ __launch_bounds__(512) void attn_prep(const float* __restrict__ K,
                                                 const float* __restrict__ V,
                                                 float* __restrict__ out,
                                                 char* __restrict__ ws) {
  const int t = blockIdx.x * 512 + threadIdx.x;
  if (t < 131072) {
    // K frag: lane holds K[key=lane&31][d0..d0+7], d0 = s*16 + (lane>>5)*8
    int kt = t >> 9, idx = t & 511;
    int lane = idx & 63, s = idx >> 6;
    int key = kt * 32 + (lane & 31);
    int d0  = s * 16 + (lane >> 5) * 8;
    const float4* src = (const float4*)(K + (size_t)key * D_K + d0);
    float4 a = src[0], b = src[1];
    float f[8] = {a.x, a.y, a.z, a.w, b.x, b.y, b.z, b.w};
    UH8 h;
    #pragma unroll
    for (int j = 0; j < 8; ++j) h.h[j] = (_Float16)f[j];
    ((uint4*)(ws + KF_OFF))[(size_t)kt * 512 + idx] = h.q;
  } else if (t < 262144) {
    // V frag: lane holds V[kb..kb+7][d], d = c*32 + (lane&31)
    int g = t - 131072;
    int kt = g >> 9, idx = g & 511;
    int lane = idx & 63, c = (idx >> 6) & 3, kstep = idx >> 8;
    int d  = c * 32 + (lane & 31);
    int kb = kt * 32 + kstep * 16 + (lane >> 5) * 8;
    UH8 h;
    #pragma unroll
    for (int j = 0; j < 8; ++j) h.h[j] = (_Float16)V[(size_t)(kb + j) * D_K + d];
    ((uint4*)(ws + VF_OFF))[(size_t)kt * 512 + idx] = h.q;
  } else if (ZOUT && t < 327680) {
    int i = t - 262144;  // zero out: 65536 threads x 4 float4
    float4 z = make_float4(0.f, 0.f, 0.f, 0.f);
    float4* o4 = (float4*)out;
    #pragma unroll
    for (int j = 0; j < 4; ++j) o4[(size_t)i * 4 + j] = z;
  } else if (ZOUT && t < 329728) {
    int i = t - 327680;  // zero ws_l: 2048 float4
    ((float4*)(ws + WS_L_OFF))[i] = make_float4(0.f, 0.f, 0.f, 0.f);
  }
}

// ---------------- main attention kernel ----------------
template <bool PARTIAL>
__global__ __launch_bounds__(256, 2)
void attn_main(const float* __restrict__ Qg, float* __restrict__ out,
               char* __restrict__ ws) {
  __shared__ uint4 Ks[2][1024];   // dbuf: K frags of 2 subtiles (16 KB each)

  const int tid   = threadIdx.x;
  const int wave  = tid >> 6;
  const int lane  = tid & 63;
  const int lrow  = lane & 31;
  const int lhalf = lane >> 5;

  const int blk = blockIdx.x;
  const int ks  = blk & 7;               // k-slice (XCD-pinned by dispatch % 8)
  const int qb  = blk >> 3;              // 0..63
  const int qw  = qb * 128 + wave * 32;  // wave's 32-row q base

  float* ws_l = (float*)(ws + WS_L_OFF);

  // ---- Q B-frags: lane holds Q[q=lane&31][d=(lane>>5)*8+j + 16s], scaled ----
  f16x8 qf[8];
  {
    const int q = qw + lrow;
    #pragma unroll
    for (int s = 0; s < 8; ++s) {
      const float4* src = (const float4*)(Qg + (size_t)q * D_K + s * 16 + lhalf * 8);
      float4 a = src[0], b = src[1];
      float f[8] = {a.x, a.y, a.z, a.w, b.x, b.y, b.z, b.w};
      UH8 h;
      #pragma unroll
      for (int j = 0; j < 8; ++j) h.h[j] = (_Float16)(f[j] * CSCALE);
      qf[s] = h.v;
    }
  }

  f32x16 O0{}, O1{}, O2{}, O3{};
  float lsum = 0.f;

  const uint4* KFg = (const uint4*)(ws + KF_OFF);
  const uint4* VFg = (const uint4*)(ws + VF_OFF);

  // prologue: stage K for iter 0 (16 KB, 4 async16/thread)
  {
    const size_t base = (size_t)ks * 16384;   // ks*32 tiles * 512
    #pragma unroll
    for (int i = 0; i < 4; ++i)
      async16(KFg + base + i * 256 + tid, &Ks[0][i * 256 + tid]);
  }

  for (int it = 0; it < ITERS2; ++it) {
    const int buf = it & 1;
    const int kt0 = ks * 32 + it * 2;          // subtile 0 tile index
    __syncthreads();   // drains async K loads -> Ks[buf] ready

    if (it + 1 < ITERS2) {
      const size_t base = ((size_t)kt0 + 2) * 512;
      #pragma unroll
      for (int i = 0; i < 4; ++i)
        async16(KFg + base + i * 256 + tid, &Ks[buf ^ 1][i * 256 + tid]);
    }

    // ---- issue V loads for subtile 0 (consumed after QK+softmax ~700 cyc) ----
    uint4 vr0[8];
    {
      const uint4* vb = VFg + (size_t)kt0 * 512 + lane;
      #pragma unroll
      for (int f = 0; f < 8; ++f) vr0[f] = vb[f * 64];
    }

    #pragma unroll
    for (int u = 0; u < 2; ++u) {
      const uint4* sub = &Ks[buf][u * 512];

      // ---- S^T = K Q^T : dual accumulators ----
      f32x16 Sa{}, Sb{};
      #pragma unroll
      for (int s = 0; s < 4; ++s) {
        f16x8 ka = __builtin_bit_cast(f16x8, sub[(2 * s    ) * 64 + lane]);
        f16x8 kb = __builtin_bit_cast(f16x8, sub[(2 * s + 1) * 64 + lane]);
        Sa = __builtin_amdgcn_mfma_f32_32x32x16_f16(ka, qf[2 * s    ], Sa, 0, 0, 0);
        Sb = __builtin_amdgcn_mfma_f32_32x32x16_f16(kb, qf[2 * s + 1], Sb, 0, 0, 0);
      }

      // ---- P^T = exp2(Sa+Sb); per-lane row sums; pack to fp16 pairs ----
      unsigned pk[8];
      #pragma unroll
      for (int i = 0; i < 8; ++i) {
        float p0 = __builtin_amdgcn_exp2f(Sa[2 * i]     + Sb[2 * i]);
        float p1 = __builtin_amdgcn_exp2f(Sa[2 * i + 1] + Sb[2 * i + 1]);
        lsum += p0 + p1;
        pk[i] = __builtin_bit_cast(unsigned, __builtin_amdgcn_cvt_pkrtz(p0, p1));
      }

      // ---- in-register transpose to P A-frags (lane<->lane+32 half swap) ----
      unsigned s0 = __shfl_xor(pk[0], 32), s1 = __shfl_xor(pk[1], 32);
      unsigned s2 = __shfl_xor(pk[2], 32), s3 = __shfl_xor(pk[3], 32);
      unsigned s4 = __shfl_xor(pk[4], 32), s5 = __shfl_xor(pk[5], 32);
      unsigned s6 = __shfl_xor(pk[6], 32), s7 = __shfl_xor(pk[7], 32);
      UF4 A0, A1;
      A0.u[0] = lhalf ? s2 : pk[0];
      A0.u[1] = lhalf ? s3 : pk[1];
      A0.u[2] = lhalf ? pk[2] : s0;
      A0.u[3] = lhalf ? pk[3] : s1;
      A1.u[0] = lhalf ? s6 : pk[4];
      A1.u[1] = lhalf ? s7 : pk[5];
      A1.u[2] = lhalf ? pk[6] : s4;
      A1.u[3] = lhalf ? pk[7] : s5;

      // ---- issue V loads for subtile 1 (consumed after softmax(1)) ----
      uint4 vr1[8];
      if (u == 0) {
        const uint4* vb = VFg + ((size_t)kt0 + 1) * 512 + lane;
        #pragma unroll
        for (int f = 0; f < 8; ++f) vr1[f] = vb[f * 64];
      }

      // ---- O += P V : 8 MFMAs from registers (no LDS wait) ----
      const uint4* vr = (u == 0) ? vr0 : vr0;  // placeholder; see below
      #pragma unroll
      for (int kstep = 0; kstep < 2; ++kstep) {
        f16x8 pf = kstep ? A1.v : A0.v;
        f16x8 v0, v1, v2, v3;
        if (u == 0) {
          v0 = __builtin_bit_cast(f16x8, vr0[kstep * 4 + 0]);
          v1 = __builtin_bit_cast(f16x8, vr0[kstep * 4 + 1]);
          v2 = __builtin_bit_cast(f16x8, vr0[kstep * 4 + 2]);
          v3 = __builtin_bit_cast(f16x8, vr0[kstep * 4 + 3]);
        } else {
          v0 = __builtin_bit_cast(f16x8, vr0[kstep * 4 + 0]);
          v1 = __builtin_bit_cast(f16x8, vr0[kstep * 4 + 1]);
          v2 = __builtin_bit_cast(f16x8, vr0[kstep * 4 + 2]);
          v3 = __builtin_bit_cast(f16x8, vr0[kstep * 4 + 3]);
        }
        O0 = __builtin_amdgcn_mfma_f32_32x32x16_f16(pf, v0, O0, 0, 0, 0);
        O1 = __builtin_amdgcn_mfma_f32_32x32x16_f16(pf, v1, O1, 0, 0, 0);
        O2 = __builtin_amdgcn_mfma_f32_32x32x16_f16(pf, v2, O2, 0, 0, 0);
        O3 = __builtin_amdgcn_mfma_f32_32x32x16_f16(pf, v3, O3, 0, 0, 0);
      }
      // rotate vr1 -> vr0 for the u==1 pass
      if (u == 0) {
        #pragma unroll
        for (int f = 0; f < 8; ++f) vr0[f] = vr1[f];
      }
    }
  }

  // ---- epilogue ----
  lsum += __shfl_xor(lsum, 32);           // combine the two key-halves

  if (PARTIAL) {
    if (lhalf == 0) ws_l[ks * S_LEN + qw + lrow] = lsum;   // plain store
    float* obase = (ks == 0) ? out
                 : (float*)(ws + PART_OFF) + (size_t)(ks - 1) * S_LEN * D_K;
    #pragma unroll
    for (int r = 0; r < 16; ++r) {
      int row = (r & 3) + 8 * (r >> 2) + 4 * lhalf;
      float* dst = obase + (size_t)(qw + row) * D_K + lrow;
      dst[ 0] = O0[r];
      dst[32] = O1[r];
      dst[64] = O2[r];
      dst[96] = O3[r];
    }
  } else {
    if (lhalf == 0) atomicAdd(ws_l + qw + lrow, lsum);
    #pragma unroll
    for (int r = 0; r < 16; ++r) {
      int row = (r & 3) + 8 * (r >> 2) + 4 * lhalf;
      float* dst = out + (size_t)(qw + row) * D_K + lrow;
      atomicAdd(dst +  0, O0[r]);
      atomicAdd(dst + 32, O1[r]);
      atomicAdd(dst + 64, O2[r]);
      atomicAdd(dst + 96, O3[r]);
    }
  }
}

// ---------------- reduce partials (nparts>0) or just normalize (nparts=0) ----
__global__ __launch_bounds__(256) void attn_norm(float* __restrict__ out,
                                                 const float* __restrict__ lpart,
                                                 const float* __restrict__ opart,
                                                 int nparts) {
  int i = blockIdx.x * 256 + threadIdx.x;  // float4 index, 262144 total
  int q = i >> 5;
  float4* o4 = (float4*)out;
  float4 acc = o4[i];
  float l = lpart[q];
  for (int s = 1; s <= nparts; ++s) {
    float4 p = ((const float4*)opart)[(size_t)(s - 1) * 262144 + i];
    acc.x += p.x; acc.y += p.y; acc.z += p.z; acc.w += p.w;
    l += lpart[s * S_LEN + q];
  }
  float inv = 1.0f / l;
  acc.x *= inv; acc.y *= inv; acc.z *= inv; acc.w *= inv;
  o4[i] = acc;
}

extern "C" void kernel_launch(void* const* d_in, const int* in_sizes, int n_in,
                              void* d_out, int out_size, void* d_ws, size_t ws_size,
                              hipStream_t stream) {
  const float* q = (const float*)d_in[0];
  const float* k = (const float*)d_in[1];
  const float* v = (const float*)d_in[2];
  float* out = (float*)d_out;
  char* ws = (char*)d_ws;

  if (ws_size >= WS_NEED) {
    attn_prep<false><<<dim3(512), dim3(512), 0, stream>>>(k, v, out, ws);
    attn_main<true><<<dim3(512), dim3(256), 0, stream>>>(q, out, ws);
    attn_norm<<<dim3(1024), dim3(256), 0, stream>>>(
        out, (const float*)(ws + WS_L_OFF), (const float*)(ws + PART_OFF), 7);
  } else {
    attn_prep<true><<<dim3(645), dim3(512), 0, stream>>>(k, v, out, ws);
    attn_main<false><<<dim3(512), dim3(256), 0, stream>>>(q, out, ws);
    attn_norm<<<dim3(1024), dim3(256), 0, stream>>>(
        out, (const float*)(ws + WS_L_OFF), (const float*)(ws + PART_OFF), 0);
  }
}